// Round 1
// baseline (670.563 us; speedup 1.0000x reference)
//
#include <hip/hip_runtime.h>
#include <hip/hip_bf16.h>
#include <stdint.h>
#include <stddef.h>

typedef __bf16 bf16_t;
typedef __bf16 bf16x2 __attribute__((ext_vector_type(2)));
typedef __bf16 bf16x4 __attribute__((ext_vector_type(4)));
typedef __bf16 bf16x8 __attribute__((ext_vector_type(8)));
typedef float f32x4 __attribute__((ext_vector_type(4)));

#define FP8_MAX 448.0f
#define ACT_EPS 1e-4f
#define W_EPS   1e-6f

__device__ __forceinline__ float wave_max(float v) {
#pragma unroll
  for (int off = 32; off > 0; off >>= 1)
    v = fmaxf(v, __shfl_xor(v, off, 64));
  return v;
}

// ---------------- Quant-dequant activations: per (row, 128-col tile) ----------------
// One wave per 128-element tile; lane handles 2 consecutive elements.
__global__ __launch_bounds__(256) void quant_x_kernel(const float* __restrict__ x,
                                                      bf16_t* __restrict__ xdq,
                                                      int K) {
  const int wave = threadIdx.x >> 6, lane = threadIdx.x & 63;
  const int tile = blockIdx.x * 4 + wave;
  const int ktiles = K >> 7;
  const int row = tile / ktiles, kt = tile % ktiles;
  const size_t base = (size_t)row * K + (size_t)kt * 128 + lane * 2;
  const float2 v = *(const float2*)(x + base);
  const float amax = wave_max(fmaxf(fabsf(v.x), fabsf(v.y)));
  const float safe = fmaxf(amax, ACT_EPS);
  const float r = FP8_MAX / safe;   // matches ref: FP8_MAX / safe, then mul
  const float s = safe / FP8_MAX;   // stored scale
  const int pk = __builtin_amdgcn_cvt_pk_fp8_f32(v.x * r, v.y * r, 0, false);
  const float d0 = __builtin_amdgcn_cvt_f32_fp8(pk, 0) * s;
  const float d1 = __builtin_amdgcn_cvt_f32_fp8(pk, 1) * s;
  bf16x2 o;
  o.x = (bf16_t)d0;
  o.y = (bf16_t)d1;
  *(bf16x2*)(xdq + base) = o;
}

// ---------------- Quant-dequant weights: per 128x128 block ----------------
// One 256-thread block per 128x128 weight block. Two threads per row (64 cols each).
__global__ __launch_bounds__(256) void quant_w_kernel(const float* __restrict__ w,
                                                      bf16_t* __restrict__ wdq,
                                                      int K) {
  const int ktiles = K >> 7;
  const int nb = blockIdx.x / ktiles, kb = blockIdx.x % ktiles;
  const int t = threadIdx.x;
  const int row = t >> 1;   // 0..127
  const int half = t & 1;   // cols half*64 .. half*64+63
  const float* src = w + (size_t)(nb * 128 + row) * K + kb * 128 + half * 64;
  float amax = 0.f;
#pragma unroll
  for (int i = 0; i < 16; ++i) {
    float4 v = *(const float4*)(src + i * 4);
    amax = fmaxf(amax, fmaxf(fmaxf(fabsf(v.x), fabsf(v.y)),
                             fmaxf(fabsf(v.z), fabsf(v.w))));
  }
  amax = wave_max(amax);
  __shared__ float sm[4];
  const int wave = t >> 6, lane = t & 63;
  if (lane == 0) sm[wave] = amax;
  __syncthreads();
  if (t == 0) sm[0] = fmaxf(fmaxf(sm[0], sm[1]), fmaxf(sm[2], sm[3]));
  __syncthreads();
  const float safe = fmaxf(sm[0], W_EPS);
  const float r = FP8_MAX / safe;
  const float s = safe / FP8_MAX;
  bf16_t* dst = wdq + (size_t)(nb * 128 + row) * K + kb * 128 + half * 64;
#pragma unroll
  for (int i = 0; i < 16; ++i) {
    float4 v = *(const float4*)(src + i * 4);  // L2/L3 hit on re-read
    int pk = __builtin_amdgcn_cvt_pk_fp8_f32(v.x * r, v.y * r, 0, false);
    pk = __builtin_amdgcn_cvt_pk_fp8_f32(v.z * r, v.w * r, pk, true);
    bf16x4 o;
    o.x = (bf16_t)(__builtin_amdgcn_cvt_f32_fp8(pk, 0) * s);
    o.y = (bf16_t)(__builtin_amdgcn_cvt_f32_fp8(pk, 1) * s);
    o.z = (bf16_t)(__builtin_amdgcn_cvt_f32_fp8(pk, 2) * s);
    o.w = (bf16_t)(__builtin_amdgcn_cvt_f32_fp8(pk, 3) * s);
    *(bf16x4*)(dst + i * 4) = o;
  }
}

// ---------------- bf16 GEMM: C[M,N] = A[M,K] * B[N,K]^T (m97 structure) ----------------
__device__ __forceinline__ void async_copy16(void* gptr, void* lptr) {
  __builtin_amdgcn_global_load_lds(
      (__attribute__((address_space(1))) void*)gptr,
      (__attribute__((address_space(3))) void*)lptr, 16, 0, 0);
}

__global__ __launch_bounds__(256) void gemm_bf16_bt(const bf16_t* __restrict__ A,
                                                    const bf16_t* __restrict__ B,
                                                    float* __restrict__ C,
                                                    int M, int N, int K) {
  // 128x128 C tile per block, 4 waves, each wave does 64x64 (4x4 of 16x16x32 MFMA).
  __shared__ bf16_t As[128 * 64];  // row-major [row][k], row stride 64 bf16 (no pad: global_load_lds)
  __shared__ bf16_t Bs[128 * 64];

  const int t = threadIdx.x;
  const int wave = t >> 6, lane = t & 63;
  const int m0 = blockIdx.y * 128, n0 = blockIdx.x * 128;
  const int wm = (wave >> 1) * 64, wn = (wave & 1) * 64;
  const int fr = lane & 15;   // row within 16x16 frag
  const int fq = lane >> 4;   // quad -> k offset fq*8, D-row base fq*4

  f32x4 acc[4][4] = {};

  for (int kt = 0; kt < K; kt += 64) {
    // Stage A,B tiles: 128 rows x 64 k of bf16 = 16KB each = 1024 chunks of 16B.
    // chunk = j*256 + t; row = chunk>>3, colchunk = chunk&7. LDS offset = chunk*16.
#pragma unroll
    for (int j = 0; j < 4; ++j) {
      const int chunk = j * 256 + t;
      const int row = chunk >> 3, cc = chunk & 7;
      char* la = (char*)As + (size_t)(j * 256 + wave * 64) * 16;  // wave-uniform base
      char* lb = (char*)Bs + (size_t)(j * 256 + wave * 64) * 16;
      async_copy16((void*)(A + (size_t)(m0 + row) * K + kt + cc * 8), la);
      async_copy16((void*)(B + (size_t)(n0 + row) * K + kt + cc * 8), lb);
    }
    __syncthreads();

#pragma unroll
    for (int ks = 0; ks < 64; ks += 32) {
      bf16x8 af[4], bfr[4];
#pragma unroll
      for (int i = 0; i < 4; ++i)
        af[i] = *(const bf16x8*)&As[(wm + i * 16 + fr) * 64 + ks + fq * 8];
#pragma unroll
      for (int i = 0; i < 4; ++i)
        bfr[i] = *(const bf16x8*)&Bs[(wn + i * 16 + fr) * 64 + ks + fq * 8];
#pragma unroll
      for (int i = 0; i < 4; ++i)
#pragma unroll
        for (int j = 0; j < 4; ++j)
          acc[i][j] = __builtin_amdgcn_mfma_f32_16x16x32_bf16(af[i], bfr[j], acc[i][j], 0, 0, 0);
    }
    __syncthreads();
  }

  // Epilogue: D layout col = lane&15, row = fq*4 + reg.
#pragma unroll
  for (int i = 0; i < 4; ++i) {
    const int row0 = m0 + wm + i * 16 + fq * 4;
#pragma unroll
    for (int j = 0; j < 4; ++j) {
      const int col = n0 + wn + j * 16 + fr;
      float* cp = C + (size_t)row0 * N + col;
#pragma unroll
      for (int r = 0; r < 4; ++r) cp[(size_t)r * N] = acc[i][j][r];
    }
  }
}

extern "C" void kernel_launch(void* const* d_in, const int* in_sizes, int n_in,
                              void* d_out, int out_size, void* d_ws, size_t ws_size,
                              hipStream_t stream) {
  const float* x = (const float*)d_in[0];    // [M, K] fp32
  const float* w = (const float*)d_in[1];    // [N, K] fp32
  float* out = (float*)d_out;                // [M, N] fp32

  const int K = 4096;
  const int M = in_sizes[0] / K;  // 8192
  const int N = in_sizes[1] / K;  // 4096

  bf16_t* xdq = (bf16_t*)d_ws;                 // M*K bf16 = 67.1 MB
  bf16_t* wdq = xdq + (size_t)M * K;           // N*K bf16 = 33.5 MB

  // 1) quant-dequant activations (1x128 tiles): one wave per tile
  quant_x_kernel<<<(M * (K / 128)) / 4, 256, 0, stream>>>(x, xdq, K);
  // 2) quant-dequant weights (128x128 blocks): one block per weight block
  quant_w_kernel<<<(N / 128) * (K / 128), 256, 0, stream>>>(w, wdq, K);
  // 3) bf16 GEMM with B^T input layout
  dim3 grid(N / 128, M / 128);
  gemm_bf16_bt<<<grid, 256, 0, stream>>>(xdq, wdq, out, M, N, K);
}

// Round 2
// 589.732 us; speedup vs baseline: 1.1371x; 1.1371x over previous
//
#include <hip/hip_runtime.h>
#include <hip/hip_bf16.h>
#include <stdint.h>
#include <stddef.h>

typedef __bf16 bf16_t;
typedef __bf16 bf16x4 __attribute__((ext_vector_type(4)));
typedef __bf16 bf16x8 __attribute__((ext_vector_type(8)));
typedef float f32x4 __attribute__((ext_vector_type(4)));

#define FP8_MAX 448.0f
#define ACT_EPS 1e-4f
#define W_EPS   1e-6f

// ---------------- Quant-dequant activations: per (row, 128-col tile) ----------------
// 32 lanes per tile (float4 each), 8 tiles per 256-thread block.
__global__ __launch_bounds__(256) void quant_x_kernel(const float* __restrict__ x,
                                                      bf16_t* __restrict__ xdq,
                                                      int K) {
  const int t = threadIdx.x;
  const int lane32 = t & 31;
  const int ktiles = K >> 7;
  const int tile = blockIdx.x * 8 + (t >> 5);
  const int row = tile / ktiles, kt = tile % ktiles;
  const size_t base = (size_t)row * K + (size_t)kt * 128 + lane32 * 4;
  const float4 v = *(const float4*)(x + base);
  float amax = fmaxf(fmaxf(fabsf(v.x), fabsf(v.y)), fmaxf(fabsf(v.z), fabsf(v.w)));
#pragma unroll
  for (int off = 16; off > 0; off >>= 1)
    amax = fmaxf(amax, __shfl_xor(amax, off, 64));  // stays within aligned 32-group
  const float safe = fmaxf(amax, ACT_EPS);
  const float r = FP8_MAX / safe;   // matches ref op order
  const float s = safe / FP8_MAX;
  int pk = __builtin_amdgcn_cvt_pk_fp8_f32(v.x * r, v.y * r, 0, false);
  pk = __builtin_amdgcn_cvt_pk_fp8_f32(v.z * r, v.w * r, pk, true);
  bf16x4 o;
  o.x = (bf16_t)(__builtin_amdgcn_cvt_f32_fp8(pk, 0) * s);
  o.y = (bf16_t)(__builtin_amdgcn_cvt_f32_fp8(pk, 1) * s);
  o.z = (bf16_t)(__builtin_amdgcn_cvt_f32_fp8(pk, 2) * s);
  o.w = (bf16_t)(__builtin_amdgcn_cvt_f32_fp8(pk, 3) * s);
  *(bf16x4*)(xdq + base) = o;
}

// ---------------- Quant-dequant weights: per 128x128 block ----------------
// 256 threads per block; thread t covers row (i*8 + t>>5), cols (t&31)*4.
// Values held in registers across the amax reduction (no re-read).
__global__ __launch_bounds__(256) void quant_w_kernel(const float* __restrict__ w,
                                                      bf16_t* __restrict__ wdq,
                                                      int K) {
  const int ktiles = K >> 7;
  const int nb = blockIdx.x / ktiles, kb = blockIdx.x % ktiles;
  const int t = threadIdx.x;
  const int r8 = t >> 5;        // 0..7
  const int c4 = (t & 31) * 4;  // col offset 0..124
  const size_t rbase = (size_t)(nb * 128) * K + kb * 128 + c4;

  float4 v[16];
  float amax = 0.f;
#pragma unroll
  for (int i = 0; i < 16; ++i) {
    v[i] = *(const float4*)(w + rbase + (size_t)(i * 8 + r8) * K);
    amax = fmaxf(amax, fmaxf(fmaxf(fabsf(v[i].x), fabsf(v[i].y)),
                             fmaxf(fabsf(v[i].z), fabsf(v[i].w))));
  }
#pragma unroll
  for (int off = 32; off > 0; off >>= 1)
    amax = fmaxf(amax, __shfl_xor(amax, off, 64));
  __shared__ float sm[4];
  if ((t & 63) == 0) sm[t >> 6] = amax;
  __syncthreads();
  const float bmax = fmaxf(fmaxf(sm[0], sm[1]), fmaxf(sm[2], sm[3]));
  const float safe = fmaxf(bmax, W_EPS);
  const float r = FP8_MAX / safe;
  const float s = safe / FP8_MAX;
  bf16_t* dst = wdq + rbase;
#pragma unroll
  for (int i = 0; i < 16; ++i) {
    int pk = __builtin_amdgcn_cvt_pk_fp8_f32(v[i].x * r, v[i].y * r, 0, false);
    pk = __builtin_amdgcn_cvt_pk_fp8_f32(v[i].z * r, v[i].w * r, pk, true);
    bf16x4 o;
    o.x = (bf16_t)(__builtin_amdgcn_cvt_f32_fp8(pk, 0) * s);
    o.y = (bf16_t)(__builtin_amdgcn_cvt_f32_fp8(pk, 1) * s);
    o.z = (bf16_t)(__builtin_amdgcn_cvt_f32_fp8(pk, 2) * s);
    o.w = (bf16_t)(__builtin_amdgcn_cvt_f32_fp8(pk, 3) * s);
    *(bf16x4*)(dst + (size_t)(i * 8 + r8) * K) = o;
  }
}

// ---------------- bf16 GEMM: C[M,N] = A[M,K] * B[N,K]^T ----------------
// m97 structure + XOR-swizzled LDS chunk layout to kill ds_read bank conflicts.
// LDS slot (row, sc) holds global k-chunk (sc ^ (row&7)); each chunk = 8 bf16 = 16B.
__device__ __forceinline__ void async_copy16(const void* gptr, void* lptr) {
  __builtin_amdgcn_global_load_lds(
      (const __attribute__((address_space(1))) void*)gptr,
      (__attribute__((address_space(3))) void*)lptr, 16, 0, 0);
}

__global__ __launch_bounds__(256) void gemm_bf16_bt(const bf16_t* __restrict__ A,
                                                    const bf16_t* __restrict__ B,
                                                    float* __restrict__ C,
                                                    int M, int N, int K) {
  __shared__ bf16_t As[128 * 64];  // [row][k], row stride 64 bf16, chunks XOR-swizzled
  __shared__ bf16_t Bs[128 * 64];

  const int t = threadIdx.x;
  const int wave = t >> 6, lane = t & 63;
  const int m0 = blockIdx.y * 128, n0 = blockIdx.x * 128;
  const int wm = (wave >> 1) * 64, wn = (wave & 1) * 64;
  const int fr = lane & 15;   // row within 16x16 frag
  const int fq = lane >> 4;   // quad -> k-chunk fq, D-row base fq*4

  f32x4 acc[4][4] = {};

  for (int kt = 0; kt < K; kt += 64) {
    // Stage 128 rows x 64 k bf16 = 16KB each (1024 x 16B chunks).
    // LDS slot for chunk = j*256+t is linear (wave-uniform base + lane*16);
    // the GLOBAL chunk fetched into slot (row, sc) is sc ^ (row&7).
#pragma unroll
    for (int j = 0; j < 4; ++j) {
      const int chunk = j * 256 + t;
      const int row = chunk >> 3;
      const int gc = (chunk & 7) ^ (row & 7);
      char* la = (char*)As + (size_t)(j * 256 + wave * 64) * 16;  // wave-uniform base
      char* lb = (char*)Bs + (size_t)(j * 256 + wave * 64) * 16;
      async_copy16((const void*)(A + (size_t)(m0 + row) * K + kt + gc * 8), la);
      async_copy16((const void*)(B + (size_t)(n0 + row) * K + kt + gc * 8), lb);
    }
    __syncthreads();

#pragma unroll
    for (int ks = 0; ks < 64; ks += 32) {
      bf16x8 af[4], bfr[4];
      const int kidx = (ks >> 3) + fq;  // 0..7
#pragma unroll
      for (int i = 0; i < 4; ++i) {
        const int ra = wm + i * 16 + fr;
        af[i] = *(const bf16x8*)&As[ra * 64 + ((kidx ^ (ra & 7)) * 8)];
      }
#pragma unroll
      for (int i = 0; i < 4; ++i) {
        const int rb = wn + i * 16 + fr;
        bfr[i] = *(const bf16x8*)&Bs[rb * 64 + ((kidx ^ (rb & 7)) * 8)];
      }
#pragma unroll
      for (int i = 0; i < 4; ++i)
#pragma unroll
        for (int j = 0; j < 4; ++j)
          acc[i][j] = __builtin_amdgcn_mfma_f32_16x16x32_bf16(af[i], bfr[j], acc[i][j], 0, 0, 0);
    }
    __syncthreads();
  }

  // Epilogue: D layout col = lane&15, row = fq*4 + reg.
#pragma unroll
  for (int i = 0; i < 4; ++i) {
    const int row0 = m0 + wm + i * 16 + fq * 4;
#pragma unroll
    for (int j = 0; j < 4; ++j) {
      const int col = n0 + wn + j * 16 + fr;
      float* cp = C + (size_t)row0 * N + col;
#pragma unroll
      for (int r = 0; r < 4; ++r) cp[(size_t)r * N] = acc[i][j][r];
    }
  }
}

extern "C" void kernel_launch(void* const* d_in, const int* in_sizes, int n_in,
                              void* d_out, int out_size, void* d_ws, size_t ws_size,
                              hipStream_t stream) {
  const float* x = (const float*)d_in[0];    // [M, K] fp32
  const float* w = (const float*)d_in[1];    // [N, K] fp32
  float* out = (float*)d_out;                // [M, N] fp32

  const int K = 4096;
  const int M = in_sizes[0] / K;  // 8192
  const int N = in_sizes[1] / K;  // 4096

  bf16_t* xdq = (bf16_t*)d_ws;                 // M*K bf16
  bf16_t* wdq = xdq + (size_t)M * K;           // N*K bf16

  quant_x_kernel<<<(M * (K / 128)) / 8, 256, 0, stream>>>(x, xdq, K);
  quant_w_kernel<<<(N / 128) * (K / 128), 256, 0, stream>>>(w, wdq, K);
  dim3 grid(N / 128, M / 128);
  gemm_bf16_bt<<<grid, 256, 0, stream>>>(xdq, wdq, out, M, N, K);
}

// Round 3
// 445.406 us; speedup vs baseline: 1.5055x; 1.3240x over previous
//
#include <hip/hip_runtime.h>
#include <hip/hip_bf16.h>
#include <stdint.h>
#include <stddef.h>

typedef float f32x4 __attribute__((ext_vector_type(4)));
typedef int   i32x4 __attribute__((ext_vector_type(4)));
typedef int   i32x8 __attribute__((ext_vector_type(8)));

#define FP8_MAX 448.0f
#define ACT_EPS 1e-4f
#define W_EPS   1e-6f

// ---------------- Quant activations -> packed fp8 + transposed scales ----------------
// 32 lanes per 1x128 tile (float4 each), 8 tiles per 256-thread block.
// xq: [M,K] fp8 bytes. sxT: [K/128, M] fp32 (transposed for coalesced GEMM staging).
__global__ __launch_bounds__(256) void quant_x_kernel(const float* __restrict__ x,
                                                      uint8_t* __restrict__ xq,
                                                      float* __restrict__ sxT,
                                                      int M, int K) {
  const int t = threadIdx.x;
  const int l32 = t & 31;
  const int ktiles = K >> 7;
  const int tile = blockIdx.x * 8 + (t >> 5);
  const int row = tile / ktiles, kt = tile % ktiles;
  const size_t base = (size_t)row * K + (size_t)kt * 128 + l32 * 4;
  const float4 v = *(const float4*)(x + base);
  float amax = fmaxf(fmaxf(fabsf(v.x), fabsf(v.y)), fmaxf(fabsf(v.z), fabsf(v.w)));
#pragma unroll
  for (int off = 16; off > 0; off >>= 1)
    amax = fmaxf(amax, __shfl_xor(amax, off, 64));  // reduces within aligned 32-group
  const float safe = fmaxf(amax, ACT_EPS);
  const float r = FP8_MAX / safe;   // matches ref op order (448/safe, then mul)
  int pk = __builtin_amdgcn_cvt_pk_fp8_f32(v.x * r, v.y * r, 0, false);
  pk = __builtin_amdgcn_cvt_pk_fp8_f32(v.z * r, v.w * r, pk, true);
  *(int*)(xq + base) = pk;   // raw fp8 bits, no dequant
  if (l32 == 0) sxT[(size_t)kt * M + row] = safe / FP8_MAX;
}

// ---------------- Quant weights (128x128 blocks) -> packed fp8 + scale ----------------
// 256 threads per block; thread t covers rows i*8 + (t>>5), cols (t&31)*4. Registers hold
// values across the reduction (no re-read). ws: [N/128, K/128].
__global__ __launch_bounds__(256) void quant_w_kernel(const float* __restrict__ w,
                                                      uint8_t* __restrict__ wq,
                                                      float* __restrict__ ws,
                                                      int K) {
  const int ktiles = K >> 7;
  const int nb = blockIdx.x / ktiles, kb = blockIdx.x % ktiles;
  const int t = threadIdx.x;
  const int r8 = t >> 5;
  const int c4 = (t & 31) * 4;
  const size_t rbase = (size_t)(nb * 128) * K + kb * 128 + c4;

  float4 v[16];
  float amax = 0.f;
#pragma unroll
  for (int i = 0; i < 16; ++i) {
    v[i] = *(const float4*)(w + rbase + (size_t)(i * 8 + r8) * K);
    amax = fmaxf(amax, fmaxf(fmaxf(fabsf(v[i].x), fabsf(v[i].y)),
                             fmaxf(fabsf(v[i].z), fabsf(v[i].w))));
  }
#pragma unroll
  for (int off = 32; off > 0; off >>= 1)
    amax = fmaxf(amax, __shfl_xor(amax, off, 64));
  __shared__ float sm[4];
  if ((t & 63) == 0) sm[t >> 6] = amax;
  __syncthreads();
  const float bmax = fmaxf(fmaxf(sm[0], sm[1]), fmaxf(sm[2], sm[3]));
  const float safe = fmaxf(bmax, W_EPS);
  const float r = FP8_MAX / safe;
  uint8_t* dst = wq + rbase;
#pragma unroll
  for (int i = 0; i < 16; ++i) {
    int pk = __builtin_amdgcn_cvt_pk_fp8_f32(v[i].x * r, v[i].y * r, 0, false);
    pk = __builtin_amdgcn_cvt_pk_fp8_f32(v[i].z * r, v[i].w * r, pk, true);
    *(int*)(dst + (size_t)(i * 8 + r8) * K) = pk;
  }
  if (t == 0) ws[nb * ktiles + kb] = safe / FP8_MAX;
}

// ---------------- fp8 GEMM with per-128-tile fp32 scales ----------------
// C[M,N] = sum_kt sx[m,kt]*sw[nb,kt] * (Aq[128-k tile] . Bq^T)
// mfma_scale_f32_16x16x128_f8f6f4 with unit e8m0 scales = pure fp8 K=128 MFMA
// (m148 structure). XOR-swizzled LDS chunks (same scheme as R2, 0 conflicts).
__device__ __forceinline__ void async_copy16(const void* gptr, void* lptr) {
  __builtin_amdgcn_global_load_lds(
      (const __attribute__((address_space(1))) void*)gptr,
      (__attribute__((address_space(3))) void*)lptr, 16, 0, 0);
}

__global__ __launch_bounds__(256) void gemm_fp8(const uint8_t* __restrict__ A,
                                                const uint8_t* __restrict__ B,
                                                const float* __restrict__ sxT,
                                                const float* __restrict__ sw,
                                                float* __restrict__ C,
                                                int M, int N, int K) {
  __shared__ __align__(16) uint8_t As[128 * 128];  // [row][k-byte], chunks XOR-swizzled
  __shared__ __align__(16) uint8_t Bs[128 * 128];
  __shared__ float Sx[128];

  const int t = threadIdx.x;
  const int wave = t >> 6, lane = t & 63;
  const int m0 = blockIdx.y * 128, n0 = blockIdx.x * 128;
  const int wm = (wave >> 1) * 64, wn = (wave & 1) * 64;
  const int fr = lane & 15;   // row within 16x16 frag
  const int fq = lane >> 4;   // quad: k-bytes fq*32..+31, D-rows fq*4..+3
  const int ktiles = K >> 7;

  f32x4 macc[4][4] = {};

  for (int kt = 0; kt < ktiles; ++kt) {
    // Stage A,B: 128 rows x 128 fp8 = 16KB each = 1024 x 16B chunks; 4 issues each.
    // LDS slot (row, sc) holds global chunk sc ^ (row&7).
#pragma unroll
    for (int j = 0; j < 4; ++j) {
      const int chunk = j * 256 + t;
      const int row = chunk >> 3;
      const int gc = (chunk & 7) ^ (row & 7);
      char* la = (char*)As + (size_t)(j * 256 + wave * 64) * 16;  // wave-uniform base
      char* lb = (char*)Bs + (size_t)(j * 256 + wave * 64) * 16;
      async_copy16((const void*)(A + (size_t)(m0 + row) * K + (size_t)kt * 128 + gc * 16), la);
      async_copy16((const void*)(B + (size_t)(n0 + row) * K + (size_t)kt * 128 + gc * 16), lb);
    }
    if (t < 128) Sx[t] = sxT[(size_t)kt * M + m0 + t];   // coalesced 512B
    const float swv = sw[(n0 >> 7) * ktiles + kt];       // uniform scalar
    __syncthreads();

    // Fragments: lane needs k-bytes [fq*32, fq*32+32) of its row = global chunks
    // fq*2, fq*2+1, each at swizzled slot c^(row&7).
    i32x8 af[4], bf[4];
#pragma unroll
    for (int i = 0; i < 4; ++i) {
      const int ra = wm + i * 16 + fr, rs = ra & 7;
      const i32x4 lo = *(const i32x4*)&As[ra * 128 + ((((fq << 1)) ^ rs) << 4)];
      const i32x4 hi = *(const i32x4*)&As[ra * 128 + ((((fq << 1) | 1) ^ rs) << 4)];
      af[i] = __builtin_shufflevector(lo, hi, 0, 1, 2, 3, 4, 5, 6, 7);
    }
#pragma unroll
    for (int i = 0; i < 4; ++i) {
      const int rb = wn + i * 16 + fr, rs = rb & 7;
      const i32x4 lo = *(const i32x4*)&Bs[rb * 128 + ((((fq << 1)) ^ rs) << 4)];
      const i32x4 hi = *(const i32x4*)&Bs[rb * 128 + ((((fq << 1) | 1) ^ rs) << 4)];
      bf[i] = __builtin_shufflevector(lo, hi, 0, 1, 2, 3, 4, 5, 6, 7);
    }

    // Per-row combined scale for this k-tile: sf[i][r] = sx[row]*sw (row = wm+i*16+fq*4+r).
    f32x4 sf[4];
#pragma unroll
    for (int i = 0; i < 4; ++i) {
      const f32x4 sx4 = *(const f32x4*)&Sx[wm + i * 16 + fq * 4];  // broadcast read
      sf[i] = sx4 * swv;
    }

#pragma unroll
    for (int i = 0; i < 4; ++i)
#pragma unroll
      for (int j = 0; j < 4; ++j) {
        const f32x4 z = {0.f, 0.f, 0.f, 0.f};
        // unit e8m0 scales (0x7F = 2^0): pure fp8 K=128 matmul
        const f32x4 p = __builtin_amdgcn_mfma_scale_f32_16x16x128_f8f6f4(
            af[i], bf[j], z, 0, 0, 0, 0x7F7F7F7F, 0, 0x7F7F7F7F);
        macc[i][j] += p * sf[i];
      }
    __syncthreads();
  }

  // Epilogue: D layout col = lane&15, row = fq*4 + reg.
#pragma unroll
  for (int i = 0; i < 4; ++i) {
    const int row0 = m0 + wm + i * 16 + fq * 4;
#pragma unroll
    for (int j = 0; j < 4; ++j) {
      const int col = n0 + wn + j * 16 + fr;
      float* cp = C + (size_t)row0 * N + col;
#pragma unroll
      for (int r = 0; r < 4; ++r) cp[(size_t)r * N] = macc[i][j][r];
    }
  }
}

extern "C" void kernel_launch(void* const* d_in, const int* in_sizes, int n_in,
                              void* d_out, int out_size, void* d_ws, size_t ws_size,
                              hipStream_t stream) {
  const float* x = (const float*)d_in[0];    // [M, K] fp32
  const float* w = (const float*)d_in[1];    // [N, K] fp32
  float* out = (float*)d_out;                // [M, N] fp32

  const int K = 4096;
  const int M = in_sizes[0] / K;  // 8192
  const int N = in_sizes[1] / K;  // 4096
  const int ktiles = K / 128;

  uint8_t* xq = (uint8_t*)d_ws;                       // M*K fp8
  uint8_t* wq = xq + (size_t)M * K;                   // N*K fp8
  float*   sxT = (float*)(wq + (size_t)N * K);        // [K/128, M]
  float*   ws  = sxT + (size_t)ktiles * M;            // [N/128, K/128]

  quant_x_kernel<<<(M * ktiles) / 8, 256, 0, stream>>>(x, xq, sxT, M, K);
  quant_w_kernel<<<(N / 128) * ktiles, 256, 0, stream>>>(w, wq, ws, K);
  dim3 grid(N / 128, M / 128);
  gemm_fp8<<<grid, 256, 0, stream>>>(xq, wq, sxT, ws, out, M, N, K);
}